// Round 4
// baseline (572.967 us; speedup 1.0000x reference)
//
#include <hip/hip_runtime.h>
#include <math.h>

#define PI_F 3.14159265358979323846f

// ---------------------------------------------------------------------------
// GF(2) deferred-CNOT bookkeeping + 4-gate fusion tables, ALL at compile time.
//
// Physical index p (12 bits, bit b <-> wire 11-b initially). M maps logical ->
// physical; CNOT(c,t): col[c] ^= col[t] (masks), row[t] ^= row[c] (M^-1 rows).
// Rot on logical wire w pairs p <-> p^col[w], role bit = parity(p & row[w]).
// Within one layer parity(col[j] & row[i]) = delta_ij (orthonormal), so any 4
// same-layer gates tile the 4096 states into 256 cosets of 16.
//
// Layer 0's Rots act on a product state -> folded analytically into init, so
// only layers 1..5 need passes: 15 passes of 4 fused gates.
//
// Per pass we need 4 pivot bits (distinct, span-independent) to enumerate
// coset representatives; we PREFER pivots >= bit 4 so that q's low nibble is
// fed directly by lane bits 0..3 -> conflict-free b64 LDS across the wave.
// The greedy grouping below picks wire groups whose span has no nonzero combo
// supported entirely in bits 0..3 (then high pivots always exist).
// ---------------------------------------------------------------------------
struct Tab {
    unsigned gmask[15][4];   // pairing masks per pass
    unsigned grole[15][4];   // role parity rows per pass
    int      ggate[15][4];   // gate index into ctab (layer*12 + wire)
    unsigned ghb[15][4];     // pivot bits (1u<<h), sorted ascending
    unsigned zrow[12];       // final measurement parity rows
};

constexpr Tab make_tab() {
    Tab tb{};
    unsigned col[12] = {}, row[12] = {};
    for (int w = 0; w < 12; ++w) { col[w] = 1u << (11 - w); row[w] = 1u << (11 - w); }
    // layer 0: Rots folded into init; apply its CNOTs (r = 1)
    for (int w = 0; w < 12; ++w) {
        const int c = w, tg = (w + 1) % 12;
        col[c] ^= col[tg];
        row[tg] ^= row[c];
    }
    int pass = 0;
    for (int l = 1; l < 6; ++l) {
        bool used[12] = {};
        for (int grp = 0; grp < 3; ++grp) {
            int sel[4] = {};
            int ns = 0;
            unsigned spanv[16] = {};
            int nspan = 1;
            // strict phase: keep span clear of low-4-only combos
            for (int w = 0; w < 12 && ns < 4; ++w) {
                if (used[w]) continue;
                bool ok = true;
                for (int s2 = 0; s2 < nspan; ++s2) {
                    unsigned comb = spanv[s2] ^ col[w];
                    if (comb != 0 && (comb & ~0xFu) == 0) { ok = false; break; }
                }
                if (ok) {
                    for (int s2 = 0; s2 < nspan; ++s2) spanv[nspan + s2] = spanv[s2] ^ col[w];
                    nspan *= 2;
                    used[w] = true; sel[ns++] = w;
                }
            }
            // relaxed fill (correct regardless; only bank behavior may degrade)
            for (int w = 0; w < 12 && ns < 4; ++w) {
                if (used[w]) continue;
                for (int s2 = 0; s2 < nspan; ++s2) spanv[nspan + s2] = spanv[s2] ^ col[w];
                nspan *= 2;
                used[w] = true; sel[ns++] = w;
            }
            for (int i = 0; i < 4; ++i) {
                tb.gmask[pass][i] = col[sel[i]];
                tb.grole[pass][i] = row[sel[i]];
                tb.ggate[pass][i] = l * 12 + sel[i];
            }
            // pivots via forward elimination, prefer bits >= 4
            unsigned em[4] = {};
            int hp[4] = {};
            for (int i = 0; i < 4; ++i) {
                unsigned e = tb.gmask[pass][i];
                for (int j = 0; j < i; ++j)
                    if (e & (1u << hp[j])) e ^= em[j];
                int h = -1;
                for (int bb = 11; bb >= 4; --bb) if (e & (1u << bb)) { h = bb; break; }
                if (h < 0) { for (int bb = 3; bb >= 0; --bb) if (e & (1u << bb)) { h = bb; break; } }
                em[i] = e; hp[i] = h;
            }
            for (int i = 0; i < 4; ++i)
                for (int j = i + 1; j < 4; ++j)
                    if (hp[j] < hp[i]) { int tmp = hp[i]; hp[i] = hp[j]; hp[j] = tmp; }
            for (int i = 0; i < 4; ++i) tb.ghb[pass][i] = 1u << hp[i];
            ++pass;
        }
        const int r = l + 1;
        for (int w = 0; w < 12; ++w) {
            const int c = w, tg = (w + r) % 12;
            col[c] ^= col[tg];
            row[tg] ^= row[c];
        }
    }
    for (int w = 0; w < 12; ++w) tb.zrow[w] = row[w];
    return tb;
}

__constant__ Tab GT = make_tab();

__device__ __forceinline__ float2 cmul(float2 A, float2 B) {
    return make_float2(A.x * B.x - A.y * B.y, A.x * B.y + A.y * B.x);
}

// ---------------------------------------------------------------------------
// One block (256 threads) per batch element. State float2 st[4096] in LDS,
// amp p at slot p. 15 fused passes; each thread owns one 16-amp coset/pass.
// ---------------------------------------------------------------------------
__global__ __launch_bounds__(256, 4) void qvl_fused(
    const float* __restrict__ v,        // (B, 512)
    const float* __restrict__ Wc,       // (12, 512)
    const float* __restrict__ bc,       // (12,)
    const float* __restrict__ weights,  // (6, 12, 3)
    float* __restrict__ out)            // (B, 12)
{
    __shared__ float2 st[4096];     // 32 KB state
    __shared__ float  ctab[72][8];  // Rot coefficients
    __shared__ float2 awv[12], bwv[12];
    __shared__ float  red[12][4];

    const int t    = threadIdx.x;
    const int lane = t & 63;
    const int wv   = t >> 6;
    const int b    = blockIdx.x;

    // ---- Rot coefficient table (batch-independent; per-block) --------------
    if (t < 72) {
        const float phi = weights[t * 3 + 0];
        const float th  = weights[t * 3 + 1];
        const float om  = weights[t * 3 + 2];
        const float hs = 0.5f * (phi + om), hd = 0.5f * (phi - om), ht = 0.5f * th;
        const float ctt = cosf(ht), stt = sinf(ht);
        const float cs = cosf(hs), ss = sinf(hs);
        const float cd = cosf(hd), sd = sinf(hd);
        ctab[t][0] = cs * ctt;  ctab[t][1] = -ss * ctt;   // u00
        ctab[t][2] = -cd * stt; ctab[t][3] = -sd * stt;   // u01
        ctab[t][4] = cd * stt;  ctab[t][5] = -sd * stt;   // u10
        ctab[t][6] = cs * ctt;  ctab[t][7] = ss * ctt;    // u11
    }

    // ---- x_w = tanh(v[b] . Wc[w] + bc[w]) * pi -----------------------------
    {
        const float2 vv = reinterpret_cast<const float2*>(v + b * 512)[t];
        #pragma unroll
        for (int w = 0; w < 12; ++w) {
            const float2 ww = reinterpret_cast<const float2*>(Wc + w * 512)[t];
            float p = vv.x * ww.x + vv.y * ww.y;
            #pragma unroll
            for (int s = 1; s < 64; s <<= 1) p += __shfl_xor(p, s, 64);
            if (lane == 0) red[w][wv] = p;
        }
    }
    __syncthreads();
    if (t < 12) {
        // fold RY(x) then layer-0 Rot (gate t) into per-wire 2-vectors
        const float x = tanhf(red[t][0] + red[t][1] + red[t][2] + red[t][3] + bc[t]) * PI_F;
        const float h = 0.5f * x;
        const float c = cosf(h), s = sinf(h);
        const float u00r = ctab[t][0], u00i = ctab[t][1];
        const float u01r = ctab[t][2], u01i = ctab[t][3];
        const float u10r = ctab[t][4], u10i = ctab[t][5];
        const float u11r = ctab[t][6], u11i = ctab[t][7];
        awv[t] = make_float2(u00r * c + u01r * s, u00i * c + u01i * s);
        bwv[t] = make_float2(u10r * c + u11r * s, u10i * c + u11i * s);
    }
    __syncthreads();

    // ---- init: product state over per-wire (a,b); p = k*256 + t ------------
    {
        float2 hi = (t & 1) ? bwv[11] : awv[11];   // p bit j -> wire 11-j
        #pragma unroll
        for (int j = 1; j < 8; ++j) {
            const float2 f = ((t >> j) & 1) ? bwv[11 - j] : awv[11 - j];
            hi = cmul(hi, f);
        }
        float2 fA[4], fB[4];
        #pragma unroll
        for (int m = 0; m < 4; ++m) {
            const float2 f8  = (m & 1) ? bwv[3] : awv[3];   // p bit 8  -> wire 3
            const float2 f9  = (m & 2) ? bwv[2] : awv[2];   // p bit 9  -> wire 2
            fA[m] = cmul(f8, f9);
            const float2 f10 = (m & 1) ? bwv[1] : awv[1];   // p bit 10 -> wire 1
            const float2 f11 = (m & 2) ? bwv[0] : awv[0];   // p bit 11 -> wire 0
            fB[m] = cmul(f10, f11);
        }
        #pragma unroll
        for (int k = 0; k < 16; ++k)
            st[k * 256 + t] = cmul(hi, cmul(fA[k & 3], fB[k >> 2]));
    }

    // ---- 15 fused passes (layers 1..5, 4 gates each) ------------------------
    #pragma unroll 1
    for (int ps = 0; ps < 15; ++ps) {
        __syncthreads();
        const unsigned m0 = GT.gmask[ps][0], m1 = GT.gmask[ps][1];
        const unsigned m2 = GT.gmask[ps][2], m3 = GT.gmask[ps][3];
        // coset representative: spread t over the 8 non-pivot bits
        unsigned q = (unsigned)t;
        q = (q << 1) - (q & (GT.ghb[ps][0] - 1u));
        q = (q << 1) - (q & (GT.ghb[ps][1] - 1u));
        q = (q << 1) - (q & (GT.ghb[ps][2] - 1u));
        q = (q << 1) - (q & (GT.ghb[ps][3] - 1u));

        float2 a[16];
        a[0]  = st[q];
        a[1]  = st[q ^ m0];
        a[2]  = st[q ^ m1];
        a[3]  = st[q ^ (m1 ^ m0)];
        a[4]  = st[q ^ m2];
        a[5]  = st[q ^ (m2 ^ m0)];
        a[6]  = st[q ^ (m2 ^ m1)];
        a[7]  = st[q ^ (m2 ^ m1 ^ m0)];
        a[8]  = st[q ^ m3];
        a[9]  = st[q ^ (m3 ^ m0)];
        a[10] = st[q ^ (m3 ^ m1)];
        a[11] = st[q ^ (m3 ^ m1 ^ m0)];
        a[12] = st[q ^ (m3 ^ m2)];
        a[13] = st[q ^ (m3 ^ m2 ^ m0)];
        a[14] = st[q ^ (m3 ^ m2 ^ m1)];
        a[15] = st[q ^ (m3 ^ m2 ^ m1 ^ m0)];

        // 4 butterfly levels; reg b's role for gate lev = bit(lev of b) ^ c
        #pragma unroll
        for (int lev = 0; lev < 4; ++lev) {
            const int g = GT.ggate[ps][lev];
            const unsigned rr = GT.grole[ps][lev];
            const int c = __popc(q & rr) & 1;
            const float u00r = ctab[g][0], u00i = ctab[g][1];
            const float u01r = ctab[g][2], u01i = ctab[g][3];
            const float u10r = ctab[g][4], u10i = ctab[g][5];
            const float u11r = ctab[g][6], u11i = ctab[g][7];
            const float Ar = c ? u11r : u00r, Ai = c ? u11i : u00i;
            const float Br = c ? u10r : u01r, Bi = c ? u10i : u01i;
            const float Cr = c ? u01r : u10r, Ci = c ? u01i : u10i;
            const float Dr = c ? u00r : u11r, Di = c ? u00i : u11i;
            #pragma unroll
            for (int bb = 0; bb < 16; ++bb) {
                if (!(bb & (1 << lev))) {
                    const int b1 = bb | (1 << lev);
                    const float2 x = a[bb], y = a[b1];
                    a[bb].x = Ar * x.x - Ai * x.y + Br * y.x - Bi * y.y;
                    a[bb].y = Ar * x.y + Ai * x.x + Br * y.y + Bi * y.x;
                    a[b1].x = Cr * x.x - Ci * x.y + Dr * y.x - Di * y.y;
                    a[b1].y = Cr * x.y + Ci * x.x + Dr * y.y + Di * y.x;
                }
            }
        }

        st[q]                         = a[0];
        st[q ^ m0]                    = a[1];
        st[q ^ m1]                    = a[2];
        st[q ^ (m1 ^ m0)]             = a[3];
        st[q ^ m2]                    = a[4];
        st[q ^ (m2 ^ m0)]             = a[5];
        st[q ^ (m2 ^ m1)]             = a[6];
        st[q ^ (m2 ^ m1 ^ m0)]        = a[7];
        st[q ^ m3]                    = a[8];
        st[q ^ (m3 ^ m0)]             = a[9];
        st[q ^ (m3 ^ m1)]             = a[10];
        st[q ^ (m3 ^ m1 ^ m0)]        = a[11];
        st[q ^ (m3 ^ m2)]             = a[12];
        st[q ^ (m3 ^ m2 ^ m0)]        = a[13];
        st[q ^ (m3 ^ m2 ^ m1)]        = a[14];
        st[q ^ (m3 ^ m2 ^ m1 ^ m0)]   = a[15];
    }
    __syncthreads();

    // ---- PauliZ expvals; p = k*256 + t, sign = parity(p & zrow) ------------
    float p2[16];
    #pragma unroll
    for (int k = 0; k < 16; ++k) {
        const float2 aa = st[k * 256 + t];
        p2[k] = aa.x * aa.x + aa.y * aa.y;
    }
    #pragma unroll
    for (int w = 0; w < 12; ++w) {
        const unsigned zr = GT.zrow[w];
        const unsigned Aw = (unsigned)__popc((unsigned)t & zr) & 1u;
        const unsigned nm = (zr >> 8) & 0xFu;
        unsigned P = 0u;
        P ^= (nm & 1u) ? 0xAAAAu : 0u;
        P ^= (nm & 2u) ? 0xCCCCu : 0u;
        P ^= (nm & 4u) ? 0xF0F0u : 0u;
        P ^= (nm & 8u) ? 0xFF00u : 0u;
        P ^= Aw ? 0xFFFFu : 0u;
        float z = 0.0f;
        #pragma unroll
        for (int k = 0; k < 16; ++k)
            z += ((P >> k) & 1u) ? -p2[k] : p2[k];
        #pragma unroll
        for (int s = 1; s < 64; s <<= 1) z += __shfl_xor(z, s, 64);
        if (lane == 0) red[w][wv] = z;
    }
    __syncthreads();
    if (t < 12)
        out[b * 12 + t] = red[t][0] + red[t][1] + red[t][2] + red[t][3];
}

extern "C" void kernel_launch(void* const* d_in, const int* in_sizes, int n_in,
                              void* d_out, int out_size, void* d_ws, size_t ws_size,
                              hipStream_t stream) {
    (void)n_in; (void)out_size; (void)d_ws; (void)ws_size;
    const float* v   = (const float*)d_in[0];
    const float* Wc  = (const float*)d_in[1];
    const float* bc  = (const float*)d_in[2];
    const float* wts = (const float*)d_in[3];
    float* out = (float*)d_out;

    const int B = in_sizes[0] / 512;
    qvl_fused<<<B, 256, 0, stream>>>(v, Wc, bc, wts, out);
}

// Round 5
// 448.137 us; speedup vs baseline: 1.2786x; 1.2786x over previous
//
#include <hip/hip_runtime.h>
#include <math.h>

#define PI_F 3.14159265358979323846f

// ---------------------------------------------------------------------------
// GF(2) deferred-CNOT bookkeeping + 4-gate fusion tables, ALL at compile time.
// See R3/R4 notes: CNOTs are index relabelings tracked in M / M^-1; Rot on
// logical wire w pairs p <-> p^col[w], role = parity(p & row[w]); within a
// layer parity(col[j] & row[i]) = delta_ij so 4 gates tile state into 256
// cosets of 16 amps. Layer 0 Rots fold into the product-state init.
// ---------------------------------------------------------------------------
struct Tab {
    unsigned gmask[15][4];   // pairing masks per pass
    unsigned grole[15][4];   // role parity rows per pass
    int      ggate[15][4];   // gate index into ctab (layer*12 + wire)
    unsigned ghb[15][4];     // pivot bits (1u<<h), sorted ascending
    unsigned zrow[12];       // final measurement parity rows
};

constexpr Tab make_tab() {
    Tab tb{};
    unsigned col[12] = {}, row[12] = {};
    for (int w = 0; w < 12; ++w) { col[w] = 1u << (11 - w); row[w] = 1u << (11 - w); }
    // layer 0: Rots folded into init; apply its CNOTs (r = 1)
    for (int w = 0; w < 12; ++w) {
        const int c = w, tg = (w + 1) % 12;
        col[c] ^= col[tg];
        row[tg] ^= row[c];
    }
    int pass = 0;
    for (int l = 1; l < 6; ++l) {
        bool used[12] = {};
        for (int grp = 0; grp < 3; ++grp) {
            int sel[4] = {};
            int ns = 0;
            unsigned spanv[16] = {};
            int nspan = 1;
            // strict phase: keep span clear of low-4-only combos
            for (int w = 0; w < 12 && ns < 4; ++w) {
                if (used[w]) continue;
                bool ok = true;
                for (int s2 = 0; s2 < nspan; ++s2) {
                    unsigned comb = spanv[s2] ^ col[w];
                    if (comb != 0 && (comb & ~0xFu) == 0) { ok = false; break; }
                }
                if (ok) {
                    for (int s2 = 0; s2 < nspan; ++s2) spanv[nspan + s2] = spanv[s2] ^ col[w];
                    nspan *= 2;
                    used[w] = true; sel[ns++] = w;
                }
            }
            // relaxed fill (correct regardless; only bank behavior may degrade)
            for (int w = 0; w < 12 && ns < 4; ++w) {
                if (used[w]) continue;
                for (int s2 = 0; s2 < nspan; ++s2) spanv[nspan + s2] = spanv[s2] ^ col[w];
                nspan *= 2;
                used[w] = true; sel[ns++] = w;
            }
            for (int i = 0; i < 4; ++i) {
                tb.gmask[pass][i] = col[sel[i]];
                tb.grole[pass][i] = row[sel[i]];
                tb.ggate[pass][i] = l * 12 + sel[i];
            }
            // pivots via forward elimination, prefer bits >= 4
            unsigned em[4] = {};
            int hp[4] = {};
            for (int i = 0; i < 4; ++i) {
                unsigned e = tb.gmask[pass][i];
                for (int j = 0; j < i; ++j)
                    if (e & (1u << hp[j])) e ^= em[j];
                int h = -1;
                for (int bb = 11; bb >= 4; --bb) if (e & (1u << bb)) { h = bb; break; }
                if (h < 0) { for (int bb = 3; bb >= 0; --bb) if (e & (1u << bb)) { h = bb; break; } }
                em[i] = e; hp[i] = h;
            }
            for (int i = 0; i < 4; ++i)
                for (int j = i + 1; j < 4; ++j)
                    if (hp[j] < hp[i]) { int tmp = hp[i]; hp[i] = hp[j]; hp[j] = tmp; }
            for (int i = 0; i < 4; ++i) tb.ghb[pass][i] = 1u << hp[i];
            ++pass;
        }
        const int r = l + 1;
        for (int w = 0; w < 12; ++w) {
            const int c = w, tg = (w + r) % 12;
            col[c] ^= col[tg];
            row[tg] ^= row[c];
        }
    }
    for (int w = 0; w < 12; ++w) tb.zrow[w] = row[w];
    return tb;
}

__constant__ Tab GT = make_tab();

__device__ __forceinline__ float2 cmul(float2 A, float2 B) {
    return make_float2(A.x * B.x - A.y * B.y, A.x * B.y + A.y * B.x);
}

// one 2x2 complex butterfly on two NAMED register operands
__device__ __forceinline__ void bf(float2& X, float2& Y,
                                   float Ar, float Ai, float Br, float Bi,
                                   float Cr, float Ci, float Dr, float Di) {
    const float2 x = X, y = Y;
    X.x = Ar * x.x - Ai * x.y + Br * y.x - Bi * y.y;
    X.y = Ar * x.y + Ai * x.x + Br * y.y + Bi * y.x;
    Y.x = Cr * x.x - Ci * x.y + Dr * y.x - Di * y.y;
    Y.y = Cr * x.y + Ci * x.x + Dr * y.y + Di * y.x;
}

// ---------------------------------------------------------------------------
// One block (256 threads) per batch element. State float2 st[4096] in LDS.
// 15 fused passes; each thread owns one 16-amp coset held in NAMED registers
// (a0..a15) — no indexable array, nothing can go to scratch (R4 lesson).
// ---------------------------------------------------------------------------
__global__ __launch_bounds__(256, 4) void qvl_fused(
    const float* __restrict__ v,        // (B, 512)
    const float* __restrict__ Wc,       // (12, 512)
    const float* __restrict__ bc,       // (12,)
    const float* __restrict__ weights,  // (6, 12, 3)
    float* __restrict__ out)            // (B, 12)
{
    __shared__ float2 st[4096];     // 32 KB state
    __shared__ float  ctab[72][8];  // Rot coefficients
    __shared__ float2 awv[12], bwv[12];
    __shared__ float  red[12][4];

    const int t    = threadIdx.x;
    const int lane = t & 63;
    const int wv   = t >> 6;
    const int b    = blockIdx.x;

    // ---- Rot coefficient table (batch-independent; per-block) --------------
    if (t < 72) {
        const float phi = weights[t * 3 + 0];
        const float th  = weights[t * 3 + 1];
        const float om  = weights[t * 3 + 2];
        const float hs = 0.5f * (phi + om), hd = 0.5f * (phi - om), ht = 0.5f * th;
        const float ctt = cosf(ht), stt = sinf(ht);
        const float cs = cosf(hs), ss = sinf(hs);
        const float cd = cosf(hd), sd = sinf(hd);
        ctab[t][0] = cs * ctt;  ctab[t][1] = -ss * ctt;   // u00
        ctab[t][2] = -cd * stt; ctab[t][3] = -sd * stt;   // u01
        ctab[t][4] = cd * stt;  ctab[t][5] = -sd * stt;   // u10
        ctab[t][6] = cs * ctt;  ctab[t][7] = ss * ctt;    // u11
    }

    // ---- x_w = tanh(v[b] . Wc[w] + bc[w]) * pi -----------------------------
    {
        const float2 vv = reinterpret_cast<const float2*>(v + b * 512)[t];
        #pragma unroll
        for (int w = 0; w < 12; ++w) {
            const float2 ww = reinterpret_cast<const float2*>(Wc + w * 512)[t];
            float p = vv.x * ww.x + vv.y * ww.y;
            #pragma unroll
            for (int s = 1; s < 64; s <<= 1) p += __shfl_xor(p, s, 64);
            if (lane == 0) red[w][wv] = p;
        }
    }
    __syncthreads();
    if (t < 12) {
        // fold RY(x) then layer-0 Rot (gate t) into per-wire 2-vectors
        const float x = tanhf(red[t][0] + red[t][1] + red[t][2] + red[t][3] + bc[t]) * PI_F;
        const float h = 0.5f * x;
        const float c = cosf(h), s = sinf(h);
        awv[t] = make_float2(ctab[t][0] * c + ctab[t][2] * s,
                             ctab[t][1] * c + ctab[t][3] * s);
        bwv[t] = make_float2(ctab[t][4] * c + ctab[t][6] * s,
                             ctab[t][5] * c + ctab[t][7] * s);
    }
    __syncthreads();

    // ---- init: product state over per-wire (a,b); p = k*256 + t ------------
    {
        float2 hi = (t & 1) ? bwv[11] : awv[11];   // p bit j -> wire 11-j
        #pragma unroll
        for (int j = 1; j < 8; ++j) {
            const float2 f = ((t >> j) & 1) ? bwv[11 - j] : awv[11 - j];
            hi = cmul(hi, f);
        }
        float2 fA[4], fB[4];
        #pragma unroll
        for (int m = 0; m < 4; ++m) {
            fA[m] = cmul((m & 1) ? bwv[3] : awv[3], (m & 2) ? bwv[2] : awv[2]);
            fB[m] = cmul((m & 1) ? bwv[1] : awv[1], (m & 2) ? bwv[0] : awv[0]);
        }
        #pragma unroll
        for (int k = 0; k < 16; ++k)
            st[k * 256 + t] = cmul(hi, cmul(fA[k & 3], fB[k >> 2]));
    }

    // ---- 15 fused passes (layers 1..5, 4 gates each) ------------------------
    #pragma unroll 1
    for (int ps = 0; ps < 15; ++ps) {
        __syncthreads();
        const unsigned m0 = GT.gmask[ps][0], m1 = GT.gmask[ps][1];
        const unsigned m2 = GT.gmask[ps][2], m3 = GT.gmask[ps][3];
        // coset representative: spread t over the 8 non-pivot bits
        unsigned q = (unsigned)t;
        q = (q << 1) - (q & (GT.ghb[ps][0] - 1u));
        q = (q << 1) - (q & (GT.ghb[ps][1] - 1u));
        q = (q << 1) - (q & (GT.ghb[ps][2] - 1u));
        q = (q << 1) - (q & (GT.ghb[ps][3] - 1u));

        const unsigned x0  = q;
        const unsigned x1  = q ^ m0;
        const unsigned x2  = q ^ m1;
        const unsigned x3  = q ^ (m1 ^ m0);
        const unsigned x4  = q ^ m2;
        const unsigned x5  = q ^ (m2 ^ m0);
        const unsigned x6  = q ^ (m2 ^ m1);
        const unsigned x7  = q ^ (m2 ^ m1 ^ m0);
        const unsigned x8  = q ^ m3;
        const unsigned x9  = q ^ (m3 ^ m0);
        const unsigned x10 = q ^ (m3 ^ m1);
        const unsigned x11 = q ^ (m3 ^ m1 ^ m0);
        const unsigned x12 = q ^ (m3 ^ m2);
        const unsigned x13 = q ^ (m3 ^ m2 ^ m0);
        const unsigned x14 = q ^ (m3 ^ m2 ^ m1);
        const unsigned x15 = q ^ (m3 ^ m2 ^ m1 ^ m0);

        float2 a0  = st[x0],  a1  = st[x1],  a2  = st[x2],  a3  = st[x3];
        float2 a4  = st[x4],  a5  = st[x5],  a6  = st[x6],  a7  = st[x7];
        float2 a8  = st[x8],  a9  = st[x9],  a10 = st[x10], a11 = st[x11];
        float2 a12 = st[x12], a13 = st[x13], a14 = st[x14], a15 = st[x15];

        #define COEFS(LEV)                                                      \
            const int   g##LEV = GT.ggate[ps][LEV];                             \
            const int   c##LEV = __popc(q & GT.grole[ps][LEV]) & 1;             \
            const float e0 = ctab[g##LEV][0], e1 = ctab[g##LEV][1];             \
            const float e2 = ctab[g##LEV][2], e3 = ctab[g##LEV][3];             \
            const float e4 = ctab[g##LEV][4], e5 = ctab[g##LEV][5];             \
            const float e6 = ctab[g##LEV][6], e7 = ctab[g##LEV][7];             \
            const float Ar = c##LEV ? e6 : e0, Ai = c##LEV ? e7 : e1;           \
            const float Br = c##LEV ? e4 : e2, Bi = c##LEV ? e5 : e3;           \
            const float Cr = c##LEV ? e2 : e4, Ci = c##LEV ? e3 : e5;           \
            const float Dr = c##LEV ? e0 : e6, Di = c##LEV ? e1 : e7;
        #define BF(X, Y) bf(X, Y, Ar, Ai, Br, Bi, Cr, Ci, Dr, Di)

        { COEFS(0)
          BF(a0,a1); BF(a2,a3); BF(a4,a5); BF(a6,a7);
          BF(a8,a9); BF(a10,a11); BF(a12,a13); BF(a14,a15); }
        { COEFS(1)
          BF(a0,a2); BF(a1,a3); BF(a4,a6); BF(a5,a7);
          BF(a8,a10); BF(a9,a11); BF(a12,a14); BF(a13,a15); }
        { COEFS(2)
          BF(a0,a4); BF(a1,a5); BF(a2,a6); BF(a3,a7);
          BF(a8,a12); BF(a9,a13); BF(a10,a14); BF(a11,a15); }
        { COEFS(3)
          BF(a0,a8); BF(a1,a9); BF(a2,a10); BF(a3,a11);
          BF(a4,a12); BF(a5,a13); BF(a6,a14); BF(a7,a15); }
        #undef COEFS
        #undef BF

        st[x0]  = a0;  st[x1]  = a1;  st[x2]  = a2;  st[x3]  = a3;
        st[x4]  = a4;  st[x5]  = a5;  st[x6]  = a6;  st[x7]  = a7;
        st[x8]  = a8;  st[x9]  = a9;  st[x10] = a10; st[x11] = a11;
        st[x12] = a12; st[x13] = a13; st[x14] = a14; st[x15] = a15;
    }
    __syncthreads();

    // ---- PauliZ expvals; p = k*256 + t, sign = parity(p & zrow) ------------
    float p2[16];
    #pragma unroll
    for (int k = 0; k < 16; ++k) {
        const float2 aa = st[k * 256 + t];
        p2[k] = aa.x * aa.x + aa.y * aa.y;
    }
    #pragma unroll
    for (int w = 0; w < 12; ++w) {
        const unsigned zr = GT.zrow[w];
        const unsigned Aw = (unsigned)__popc((unsigned)t & zr) & 1u;
        const unsigned nm = (zr >> 8) & 0xFu;
        unsigned P = 0u;
        P ^= (nm & 1u) ? 0xAAAAu : 0u;
        P ^= (nm & 2u) ? 0xCCCCu : 0u;
        P ^= (nm & 4u) ? 0xF0F0u : 0u;
        P ^= (nm & 8u) ? 0xFF00u : 0u;
        P ^= Aw ? 0xFFFFu : 0u;
        float z = 0.0f;
        #pragma unroll
        for (int k = 0; k < 16; ++k)
            z += ((P >> k) & 1u) ? -p2[k] : p2[k];
        #pragma unroll
        for (int s = 1; s < 64; s <<= 1) z += __shfl_xor(z, s, 64);
        if (lane == 0) red[w][wv] = z;
    }
    __syncthreads();
    if (t < 12)
        out[b * 12 + t] = red[t][0] + red[t][1] + red[t][2] + red[t][3];
}

extern "C" void kernel_launch(void* const* d_in, const int* in_sizes, int n_in,
                              void* d_out, int out_size, void* d_ws, size_t ws_size,
                              hipStream_t stream) {
    (void)n_in; (void)out_size; (void)d_ws; (void)ws_size;
    const float* v   = (const float*)d_in[0];
    const float* Wc  = (const float*)d_in[1];
    const float* bc  = (const float*)d_in[2];
    const float* wts = (const float*)d_in[3];
    float* out = (float*)d_out;

    const int B = in_sizes[0] / 512;
    qvl_fused<<<B, 256, 0, stream>>>(v, Wc, bc, wts, out);
}

// Round 7
// 383.143 us; speedup vs baseline: 1.4954x; 1.1696x over previous
//
#include <hip/hip_runtime.h>
#include <math.h>

#define PI_F 3.14159265358979323846f

// ---------------------------------------------------------------------------
// GF(2) deferred-CNOT bookkeeping + 4-gate fusion tables, ALL at compile time.
// CNOTs are index relabelings tracked in M / M^-1; Rot on logical wire w pairs
// p <-> p^col[w], role = parity(p & row[w]); within a layer
// parity(col[j] & row[i]) = delta_ij so 4 gates tile the state into 256
// cosets of 16 amps. Layer 0 Rots fold into the product-state init.
// ---------------------------------------------------------------------------
struct Tab {
    unsigned gmask[15][4];   // pairing masks per pass
    unsigned grole[15][4];   // role parity rows per pass
    int      ggate[15][4];   // gate index into ctab (layer*12 + wire)
    unsigned ghb[15][4];     // pivot bits (1u<<h), sorted ascending
    unsigned zrow[12];       // final measurement parity rows
};

constexpr Tab make_tab() {
    Tab tb{};
    unsigned col[12] = {}, row[12] = {};
    for (int w = 0; w < 12; ++w) { col[w] = 1u << (11 - w); row[w] = 1u << (11 - w); }
    // layer 0: Rots folded into init; apply its CNOTs (r = 1)
    for (int w = 0; w < 12; ++w) {
        const int c = w, tg = (w + 1) % 12;
        col[c] ^= col[tg];
        row[tg] ^= row[c];
    }
    int pass = 0;
    for (int l = 1; l < 6; ++l) {
        bool used[12] = {};
        for (int grp = 0; grp < 3; ++grp) {
            int sel[4] = {};
            int ns = 0;
            unsigned spanv[16] = {};
            int nspan = 1;
            // strict phase: keep span clear of low-4-only combos
            for (int w = 0; w < 12 && ns < 4; ++w) {
                if (used[w]) continue;
                bool ok = true;
                for (int s2 = 0; s2 < nspan; ++s2) {
                    unsigned comb = spanv[s2] ^ col[w];
                    if (comb != 0 && (comb & ~0xFu) == 0) { ok = false; break; }
                }
                if (ok) {
                    for (int s2 = 0; s2 < nspan; ++s2) spanv[nspan + s2] = spanv[s2] ^ col[w];
                    nspan *= 2;
                    used[w] = true; sel[ns++] = w;
                }
            }
            // relaxed fill (correct regardless; only bank behavior may degrade)
            for (int w = 0; w < 12 && ns < 4; ++w) {
                if (used[w]) continue;
                for (int s2 = 0; s2 < nspan; ++s2) spanv[nspan + s2] = spanv[s2] ^ col[w];
                nspan *= 2;
                used[w] = true; sel[ns++] = w;
            }
            for (int i = 0; i < 4; ++i) {
                tb.gmask[pass][i] = col[sel[i]];
                tb.grole[pass][i] = row[sel[i]];
                tb.ggate[pass][i] = l * 12 + sel[i];
            }
            // pivots via forward elimination, prefer bits >= 4
            unsigned em[4] = {};
            int hp[4] = {};
            for (int i = 0; i < 4; ++i) {
                unsigned e = tb.gmask[pass][i];
                for (int j = 0; j < i; ++j)
                    if (e & (1u << hp[j])) e ^= em[j];
                int h = -1;
                for (int bb = 11; bb >= 4; --bb) if (e & (1u << bb)) { h = bb; break; }
                if (h < 0) { for (int bb = 3; bb >= 0; --bb) if (e & (1u << bb)) { h = bb; break; } }
                em[i] = e; hp[i] = h;
            }
            for (int i = 0; i < 4; ++i)
                for (int j = i + 1; j < 4; ++j)
                    if (hp[j] < hp[i]) { int tmp = hp[i]; hp[i] = hp[j]; hp[j] = tmp; }
            for (int i = 0; i < 4; ++i) tb.ghb[pass][i] = 1u << hp[i];
            ++pass;
        }
        const int r = l + 1;
        for (int w = 0; w < 12; ++w) {
            const int c = w, tg = (w + r) % 12;
            col[c] ^= col[tg];
            row[tg] ^= row[c];
        }
    }
    for (int w = 0; w < 12; ++w) tb.zrow[w] = row[w];
    return tb;
}

__constant__ Tab GT = make_tab();

__device__ __forceinline__ float2 cmul(float2 A, float2 B) {
    return make_float2(A.x * B.x - A.y * B.y, A.x * B.y + A.y * B.x);
}

// one 2x2 complex butterfly on two NAMED register operands
__device__ __forceinline__ void bf(float2& X, float2& Y,
                                   float Ar, float Ai, float Br, float Bi,
                                   float Cr, float Ci, float Dr, float Di) {
    const float2 x = X, y = Y;
    X.x = Ar * x.x - Ai * x.y + Br * y.x - Bi * y.y;
    X.y = Ar * x.y + Ai * x.x + Br * y.y + Bi * y.x;
    Y.x = Cr * x.x - Ci * x.y + Dr * y.x - Di * y.y;
    Y.y = Cr * x.y + Ci * x.x + Dr * y.y + Di * y.x;
}

// ---------------------------------------------------------------------------
// One block (256 threads) per batch element. State float2 st[4096] in LDS.
// 15 fused passes; each thread owns one 16-amp coset in NAMED registers,
// addressed by a Gray-code rolling pointer (1 live address reg, R5 lesson:
// 16 CSE'd addresses + min-waves VGPR cap = partial spill -> 0.66 GB scratch).
// ---------------------------------------------------------------------------
__global__ __launch_bounds__(256) void qvl_fused(
    const float* __restrict__ v,        // (B, 512)
    const float* __restrict__ Wc,       // (12, 512)
    const float* __restrict__ bc,       // (12,)
    const float* __restrict__ weights,  // (6, 12, 3)
    float* __restrict__ out)            // (B, 12)
{
    __shared__ float2 st[4096];     // 32 KB state
    __shared__ float  ctab[72][8];  // Rot coefficients
    __shared__ float2 awv[12], bwv[12];
    __shared__ float  red[12][4];

    const int t    = threadIdx.x;
    const int lane = t & 63;
    const int wv   = t >> 6;
    const int b    = blockIdx.x;

    // ---- Rot coefficient table (batch-independent; per-block) --------------
    if (t < 72) {
        const float phi = weights[t * 3 + 0];
        const float th  = weights[t * 3 + 1];
        const float om  = weights[t * 3 + 2];
        const float hs = 0.5f * (phi + om), hd = 0.5f * (phi - om), ht = 0.5f * th;
        const float ctt = cosf(ht), stt = sinf(ht);
        const float cs = cosf(hs), ss = sinf(hs);
        const float cd = cosf(hd), sd = sinf(hd);
        ctab[t][0] = cs * ctt;  ctab[t][1] = -ss * ctt;   // u00
        ctab[t][2] = -cd * stt; ctab[t][3] = -sd * stt;   // u01
        ctab[t][4] = cd * stt;  ctab[t][5] = -sd * stt;   // u10
        ctab[t][6] = cs * ctt;  ctab[t][7] = ss * ctt;    // u11
    }

    // ---- x_w = tanh(v[b] . Wc[w] + bc[w]) * pi -----------------------------
    {
        const float2 vv = reinterpret_cast<const float2*>(v + b * 512)[t];
        #pragma unroll
        for (int w = 0; w < 12; ++w) {
            const float2 ww = reinterpret_cast<const float2*>(Wc + w * 512)[t];
            float p = vv.x * ww.x + vv.y * ww.y;
            #pragma unroll
            for (int s = 1; s < 64; s <<= 1) p += __shfl_xor(p, s, 64);
            if (lane == 0) red[w][wv] = p;
        }
    }
    __syncthreads();
    if (t < 12) {
        // fold RY(x) then layer-0 Rot (gate t) into per-wire 2-vectors
        const float x = tanhf(red[t][0] + red[t][1] + red[t][2] + red[t][3] + bc[t]) * PI_F;
        const float h = 0.5f * x;
        const float c = cosf(h), s = sinf(h);
        awv[t] = make_float2(ctab[t][0] * c + ctab[t][2] * s,
                             ctab[t][1] * c + ctab[t][3] * s);
        bwv[t] = make_float2(ctab[t][4] * c + ctab[t][6] * s,
                             ctab[t][5] * c + ctab[t][7] * s);
    }
    __syncthreads();

    // ---- init: product state over per-wire (a,b); p = k*256 + t ------------
    {
        float2 hi = (t & 1) ? bwv[11] : awv[11];   // p bit j -> wire 11-j
        #pragma unroll
        for (int j = 1; j < 8; ++j) {
            const float2 f = ((t >> j) & 1) ? bwv[11 - j] : awv[11 - j];
            hi = cmul(hi, f);
        }
        float2 fA[4], fB[4];
        #pragma unroll
        for (int m = 0; m < 4; ++m) {
            fA[m] = cmul((m & 1) ? bwv[3] : awv[3], (m & 2) ? bwv[2] : awv[2]);
            fB[m] = cmul((m & 1) ? bwv[1] : awv[1], (m & 2) ? bwv[0] : awv[0]);
        }
        #pragma unroll
        for (int k = 0; k < 16; ++k)
            st[k * 256 + t] = cmul(hi, cmul(fA[k & 3], fB[k >> 2]));
    }

    // ---- 15 fused passes (layers 1..5, 4 gates each) ------------------------
    #pragma unroll 1
    for (int ps = 0; ps < 15; ++ps) {
        __syncthreads();
        const unsigned m0 = GT.gmask[ps][0], m1 = GT.gmask[ps][1];
        const unsigned m2 = GT.gmask[ps][2], m3 = GT.gmask[ps][3];
        // coset representative: spread t over the 8 non-pivot bits
        unsigned q = (unsigned)t;
        q = (q << 1) - (q & (GT.ghb[ps][0] - 1u));
        q = (q << 1) - (q & (GT.ghb[ps][1] - 1u));
        q = (q << 1) - (q & (GT.ghb[ps][2] - 1u));
        q = (q << 1) - (q & (GT.ghb[ps][3] - 1u));

        // Gray-code load chain: one rolling address register
        unsigned ad = q;
        float2 g0  = st[ad]; ad ^= m0;
        float2 g1  = st[ad]; ad ^= m1;
        float2 g3  = st[ad]; ad ^= m0;
        float2 g2  = st[ad]; ad ^= m2;
        float2 g6  = st[ad]; ad ^= m0;
        float2 g7  = st[ad]; ad ^= m1;
        float2 g5  = st[ad]; ad ^= m0;
        float2 g4  = st[ad]; ad ^= m3;
        float2 g12 = st[ad]; ad ^= m0;
        float2 g13 = st[ad]; ad ^= m1;
        float2 g15 = st[ad]; ad ^= m0;
        float2 g14 = st[ad]; ad ^= m2;
        float2 g10 = st[ad]; ad ^= m0;
        float2 g11 = st[ad]; ad ^= m1;
        float2 g9  = st[ad]; ad ^= m0;
        float2 g8  = st[ad];

        #define COEFS(LEV)                                                      \
            const int   gi##LEV = GT.ggate[ps][LEV];                            \
            const int   cc##LEV = __popc(q & GT.grole[ps][LEV]) & 1;            \
            const float e0 = ctab[gi##LEV][0], e1 = ctab[gi##LEV][1];           \
            const float e2 = ctab[gi##LEV][2], e3 = ctab[gi##LEV][3];           \
            const float e4 = ctab[gi##LEV][4], e5 = ctab[gi##LEV][5];           \
            const float e6 = ctab[gi##LEV][6], e7 = ctab[gi##LEV][7];           \
            const float Ar = cc##LEV ? e6 : e0, Ai = cc##LEV ? e7 : e1;         \
            const float Br = cc##LEV ? e4 : e2, Bi = cc##LEV ? e5 : e3;         \
            const float Cr = cc##LEV ? e2 : e4, Ci = cc##LEV ? e3 : e5;         \
            const float Dr = cc##LEV ? e0 : e6, Di = cc##LEV ? e1 : e7;
        #define BF(X, Y) bf(X, Y, Ar, Ai, Br, Bi, Cr, Ci, Dr, Di)

        { COEFS(0)
          BF(g0,g1); BF(g2,g3); BF(g4,g5); BF(g6,g7);
          BF(g8,g9); BF(g10,g11); BF(g12,g13); BF(g14,g15); }
        { COEFS(1)
          BF(g0,g2); BF(g1,g3); BF(g4,g6); BF(g5,g7);
          BF(g8,g10); BF(g9,g11); BF(g12,g14); BF(g13,g15); }
        { COEFS(2)
          BF(g0,g4); BF(g1,g5); BF(g2,g6); BF(g3,g7);
          BF(g8,g12); BF(g9,g13); BF(g10,g14); BF(g11,g15); }
        { COEFS(3)
          BF(g0,g8); BF(g1,g9); BF(g2,g10); BF(g3,g11);
          BF(g4,g12); BF(g5,g13); BF(g6,g14); BF(g7,g15); }
        #undef COEFS
        #undef BF

        // opaque barrier on q: store addresses can't be CSE'd with load chain
        asm volatile("" : "+v"(q));

        ad = q;
        st[ad] = g0;  ad ^= m0;
        st[ad] = g1;  ad ^= m1;
        st[ad] = g3;  ad ^= m0;
        st[ad] = g2;  ad ^= m2;
        st[ad] = g6;  ad ^= m0;
        st[ad] = g7;  ad ^= m1;
        st[ad] = g5;  ad ^= m0;
        st[ad] = g4;  ad ^= m3;
        st[ad] = g12; ad ^= m0;
        st[ad] = g13; ad ^= m1;
        st[ad] = g15; ad ^= m0;
        st[ad] = g14; ad ^= m2;
        st[ad] = g10; ad ^= m0;
        st[ad] = g11; ad ^= m1;
        st[ad] = g9;  ad ^= m0;
        st[ad] = g8;
    }
    __syncthreads();

    // ---- PauliZ expvals; p = k*256 + t, sign = parity(p & zrow) ------------
    float p2[16];
    #pragma unroll
    for (int k = 0; k < 16; ++k) {
        const float2 aa = st[k * 256 + t];
        p2[k] = aa.x * aa.x + aa.y * aa.y;
    }
    #pragma unroll
    for (int w = 0; w < 12; ++w) {
        const unsigned zr = GT.zrow[w];
        const unsigned Aw = (unsigned)__popc((unsigned)t & zr) & 1u;
        const unsigned nm = (zr >> 8) & 0xFu;
        unsigned P = 0u;
        P ^= (nm & 1u) ? 0xAAAAu : 0u;
        P ^= (nm & 2u) ? 0xCCCCu : 0u;
        P ^= (nm & 4u) ? 0xF0F0u : 0u;
        P ^= (nm & 8u) ? 0xFF00u : 0u;
        P ^= Aw ? 0xFFFFu : 0u;
        float z = 0.0f;
        #pragma unroll
        for (int k = 0; k < 16; ++k)
            z += ((P >> k) & 1u) ? -p2[k] : p2[k];
        #pragma unroll
        for (int s = 1; s < 64; s <<= 1) z += __shfl_xor(z, s, 64);
        if (lane == 0) red[w][wv] = z;
    }
    __syncthreads();
    if (t < 12)
        out[b * 12 + t] = red[t][0] + red[t][1] + red[t][2] + red[t][3];
}

extern "C" void kernel_launch(void* const* d_in, const int* in_sizes, int n_in,
                              void* d_out, int out_size, void* d_ws, size_t ws_size,
                              hipStream_t stream) {
    (void)n_in; (void)out_size; (void)d_ws; (void)ws_size;
    const float* v   = (const float*)d_in[0];
    const float* Wc  = (const float*)d_in[1];
    const float* bc  = (const float*)d_in[2];
    const float* wts = (const float*)d_in[3];
    float* out = (float*)d_out;

    const int B = in_sizes[0] / 512;
    qvl_fused<<<B, 256, 0, stream>>>(v, Wc, bc, wts, out);
}